// Round 1
// baseline (279.664 us; speedup 1.0000x reference)
//
#include <hip/hip_runtime.h>

typedef unsigned short u16;
typedef unsigned int u32;
typedef __attribute__((ext_vector_type(8))) short short8;   // 8 bf16 (4 VGPRs) - MFMA A/B frag
typedef __attribute__((ext_vector_type(4))) float f32x4;    // MFMA C/D frag
typedef __attribute__((ext_vector_type(4))) u32 u32x4;      // 16B move
typedef __attribute__((ext_vector_type(4))) u16 u16x4;      // 8B move

constexpr int B_ = 2, N_ = 2048, H_ = 16;
constexpr int ROWS = B_ * N_;   // 4096

__device__ __forceinline__ float bf2f(u16 u){ union{u32 u; float f;} v; v.u = ((u32)u)<<16; return v.f; }
__device__ __forceinline__ u16 f2bf(float f){
  union{float f; u32 u;} v; v.f = f;
  u32 u = v.u; u += 0x7fffu + ((u>>16)&1u);   // RNE
  return (u16)(u>>16);
}

// ---- x fp32 -> bf16 (vectorized x4) ----
__global__ void k_conv(const float* __restrict__ x, u16* __restrict__ xb){
  int i = (blockIdx.x*blockDim.x + threadIdx.x)*4;
  f32x4 v = *(const f32x4*)(x + i);
  u16x4 o; o[0]=f2bf(v[0]); o[1]=f2bf(v[1]); o[2]=f2bf(v[2]); o[3]=f2bf(v[3]);
  *(u16x4*)(xb + i) = o;
}

// ---- W (1024x1024) -> W^T bf16 ----
__global__ void k_transpose1024(const float* __restrict__ in, u16* __restrict__ out){
  int idx = blockIdx.x*blockDim.x + threadIdx.x;   // over 1024*1024, out[n*1024+k]
  int n = idx >> 10, k = idx & 1023;
  out[idx] = f2bf(in[k*1024 + n]);
}

// ---- [Wkv | Wkvh | 0] concatenated transpose: out is (192 x 1024) bf16 ----
__global__ void k_build_wkvt(const float* __restrict__ Wkv, const float* __restrict__ Wkvh,
                             u16* __restrict__ out){
  int idx = blockIdx.x*blockDim.x + threadIdx.x;   // over 192*1024
  int n = idx >> 10, k = idx & 1023;
  float v = 0.f;
  if (n < 128)      v = Wkv[k*128 + n];
  else if (n < 160) v = Wkvh[k*32 + (n-128)];
  out[idx] = f2bf(v);
}

// ---- bf16 MFMA GEMM: C(MxN) = A(MxK) * Bt(NxK)^T, C fp32 ----
// 64x64 tile, BK=64, 256 thr = 4 waves in 2x2, each wave 32x32 (2x2 frags)
__global__ __launch_bounds__(256) void k_gemm_bt(const u16* __restrict__ A, const u16* __restrict__ Bt,
                                                 float* __restrict__ C, int M, int N, int K){
  __shared__ u16 As[64*72];   // stride 72 bf16 = 144B (16B-aligned rows, ~2-way banks)
  __shared__ u16 Bs[64*72];
  int ntile = N >> 6;
  int m0 = (blockIdx.x / ntile) << 6;
  int n0 = (blockIdx.x % ntile) << 6;
  int tid = threadIdx.x;
  int w = tid >> 6, l = tid & 63, lr = l & 15, lc = l >> 4;
  int wm = (w >> 1) * 32, wn = (w & 1) * 32;
  f32x4 acc[2][2] = {};
  for (int kt = 0; kt < K; kt += 64){
    __syncthreads();
    #pragma unroll
    for (int s = 0; s < 2; ++s){
      int chunk = tid + s*256;                 // 512 x 16B chunks per tile
      int r = chunk >> 3, c8 = (chunk & 7) << 3;
      *(u32x4*)(&As[r*72 + c8]) = *(const u32x4*)(&A[(size_t)(m0 + r)*K + kt + c8]);
      *(u32x4*)(&Bs[r*72 + c8]) = *(const u32x4*)(&Bt[(size_t)(n0 + r)*K + kt + c8]);
    }
    __syncthreads();
    short8 af[2][2], bfr[2][2];
    #pragma unroll
    for (int mf=0; mf<2; ++mf)
      #pragma unroll
      for (int c=0; c<2; ++c)
        af[mf][c] = *(const short8*)(&As[(wm + mf*16 + lr)*72 + c*32 + lc*8]);
    #pragma unroll
    for (int nf=0; nf<2; ++nf)
      #pragma unroll
      for (int c=0; c<2; ++c)
        bfr[nf][c] = *(const short8*)(&Bs[(wn + nf*16 + lr)*72 + c*32 + lc*8]);
    #pragma unroll
    for (int mf=0; mf<2; ++mf)
      #pragma unroll
      for (int nf=0; nf<2; ++nf)
        #pragma unroll
        for (int c=0; c<2; ++c)
          acc[mf][nf] = __builtin_amdgcn_mfma_f32_16x16x32_bf16(af[mf][c], bfr[nf][c], acc[mf][nf], 0,0,0);
  }
  #pragma unroll
  for (int mf=0; mf<2; ++mf)
    #pragma unroll
    for (int nf=0; nf<2; ++nf)
      #pragma unroll
      for (int r=0; r<4; ++r)
        C[(size_t)(m0 + wm + mf*16 + lc*4 + r)*N + n0 + wn + nf*16 + lr] = acc[mf][nf][r];
}

// ---- proj (ROWS x 192) -> rope'd k_rope bf16, v bf16, sigmoid gates fp32 ----
__global__ void k_postproc(const float* __restrict__ proj, u16* __restrict__ k_rope,
                           u16* __restrict__ v_bf, float* __restrict__ k_head,
                           float* __restrict__ v_head){
  int row = blockIdx.x;            // b*N + n
  int n = row & (N_-1);
  int t = threadIdx.x;             // 64
  const float* p = proj + (size_t)row*192;
  v_bf[row*64 + t] = f2bf(p[64 + t]);
  if (t < 32){
    float hv = 1.f/(1.f + __expf(-p[128 + t]));
    if (t < 16) k_head[row*16 + t] = hv; else v_head[row*16 + (t-16)] = hv;
    float inv = powf(10000.f, -(float)t*(1.f/32.f));
    float ang = (float)n * inv;
    float sn = sinf(ang), cs = cosf(ang);
    float k1 = p[t], k2 = p[32 + t];
    k_rope[row*64 + t]      = f2bf(k1*cs - k2*sn);
    k_rope[row*64 + 32 + t] = f2bf(k2*cs + k1*sn);
  }
}

// ---- q_raw fp32 -> rope + scale(0.125) -> q bf16 ----
__global__ void k_rope_q(const float* __restrict__ q_raw, u16* __restrict__ q_bf){
  int idx = blockIdx.x*blockDim.x + threadIdx.x;   // over ROWS*16*32
  int i = idx & 31;
  int h = (idx >> 5) & 15;
  int row = idx >> 9;
  int n = row & (N_-1);
  float inv = powf(10000.f, -(float)i*(1.f/32.f));
  float ang = (float)n * inv;
  float sn = sinf(ang), cs = cosf(ang);
  const float* q = q_raw + (size_t)row*1024 + h*64;
  u16* o = q_bf + (size_t)row*1024 + h*64;
  float x1 = q[i], x2 = q[i+32];
  o[i]    = f2bf(0.125f*(x1*cs - x2*sn));
  o[i+32] = f2bf(0.125f*(x2*cs + x1*sn));
}

// ---- flash attention: grid = B*H*(N/64); 4 waves x 16 q-rows; KV gates folded at staging ----
__global__ __launch_bounds__(256) void k_attn(const u16* __restrict__ q_bf, const u16* __restrict__ k_rope,
                                              const u16* __restrict__ v_bf, const float* __restrict__ k_head,
                                              const float* __restrict__ v_head, u16* __restrict__ attn_o){
  int qt = blockIdx.x & 31;
  int h  = (blockIdx.x >> 5) & 15;
  int b  = blockIdx.x >> 9;
  __shared__ u16 Ks[64*72];      // [key][hd], gate*scale folded
  __shared__ u16 Vts[64*72];     // [hd][key], gate folded (transposed for B-frag reads)
  __shared__ u16 Ps[4][16*72];   // per-wave P tile
  int tid = threadIdx.x, w = tid>>6, l = tid&63, lr = l&15, lc = l>>4;
  size_t rowbase = (size_t)b*N_;
  int qrow = qt*64 + w*16 + lr;
  size_t qoff = (rowbase + qrow)*1024 + h*64;
  short8 qf0 = *(const short8*)(&q_bf[qoff + lc*8]);
  short8 qf1 = *(const short8*)(&q_bf[qoff + 32 + lc*8]);
  float m_run[4] = {-1e30f,-1e30f,-1e30f,-1e30f};
  float l_run[4] = {0.f,0.f,0.f,0.f};
  f32x4 o[4] = {};
  const float* khp = k_head + rowbase*16 + h;
  const float* vhp = v_head + rowbase*16 + h;
  for (int kt = 0; kt <= qt; ++kt){
    __syncthreads();                       // prev iter's PV done before restage
    int kg0 = kt*64;
    #pragma unroll
    for (int s=0; s<2; ++s){
      int chunk = tid + s*256;
      int r = chunk >> 3, c8 = (chunk & 7) << 3;
      int kg = kg0 + r;
      float kh = khp[(size_t)kg*16];
      float vh = vhp[(size_t)kg*16];
      u32x4 kraw = *(const u32x4*)(&k_rope[(rowbase + kg)*64 + c8]);
      u32x4 vraw = *(const u32x4*)(&v_bf[(rowbase + kg)*64 + c8]);
      const u16* ks = (const u16*)&kraw;
      const u16* vs = (const u16*)&vraw;
      u32x4 kout; u16* ko = (u16*)&kout;
      #pragma unroll
      for (int j=0; j<8; ++j){
        ko[j] = f2bf(kh * bf2f(ks[j]));
        Vts[(c8+j)*72 + r] = f2bf(vh * bf2f(vs[j]));
      }
      *(u32x4*)(&Ks[r*72 + c8]) = kout;
    }
    __syncthreads();
    // S = Q * K^T  (16q x 64k per wave)
    f32x4 s[4] = {};
    #pragma unroll
    for (int nf=0; nf<4; ++nf){
      short8 kf0 = *(const short8*)(&Ks[(nf*16+lr)*72 + lc*8]);
      short8 kf1 = *(const short8*)(&Ks[(nf*16+lr)*72 + 32 + lc*8]);
      s[nf] = __builtin_amdgcn_mfma_f32_16x16x32_bf16(qf0, kf0, s[nf], 0,0,0);
      s[nf] = __builtin_amdgcn_mfma_f32_16x16x32_bf16(qf1, kf1, s[nf], 0,0,0);
    }
    if (kt == qt){  // causal mask only on diagonal tile
      #pragma unroll
      for (int nf=0; nf<4; ++nf)
        #pragma unroll
        for (int r=0; r<4; ++r){
          int kcol = kg0 + nf*16 + lr;
          int qg   = qt*64 + w*16 + lc*4 + r;
          if (kcol > qg) s[nf][r] = -1e30f;
        }
    }
    // online softmax (rows live across 16 consecutive lanes)
    float rm[4], al[4], ps[4];
    #pragma unroll
    for (int r=0; r<4; ++r) rm[r] = fmaxf(fmaxf(s[0][r], s[1][r]), fmaxf(s[2][r], s[3][r]));
    #pragma unroll
    for (int mk=1; mk<16; mk<<=1)
      #pragma unroll
      for (int r=0; r<4; ++r) rm[r] = fmaxf(rm[r], __shfl_xor(rm[r], mk));
    #pragma unroll
    for (int r=0; r<4; ++r){
      float mn = fmaxf(m_run[r], rm[r]);
      al[r] = __expf(m_run[r] - mn);
      m_run[r] = mn;
    }
    #pragma unroll
    for (int nf=0; nf<4; ++nf)
      #pragma unroll
      for (int r=0; r<4; ++r) s[nf][r] = __expf(s[nf][r] - m_run[r]);
    #pragma unroll
    for (int r=0; r<4; ++r) ps[r] = s[0][r]+s[1][r]+s[2][r]+s[3][r];
    #pragma unroll
    for (int mk=1; mk<16; mk<<=1)
      #pragma unroll
      for (int r=0; r<4; ++r) ps[r] += __shfl_xor(ps[r], mk);
    #pragma unroll
    for (int r=0; r<4; ++r) l_run[r] = l_run[r]*al[r] + ps[r];
    #pragma unroll
    for (int nf=0; nf<4; ++nf)
      #pragma unroll
      for (int r=0; r<4; ++r){
        o[nf][r] *= al[r];
        Ps[w][(lc*4+r)*72 + nf*16 + lr] = f2bf(s[nf][r]);   // D-layout -> LDS
      }
    __syncthreads();                       // P visible for A-frag reads
    // O += P * V
    #pragma unroll
    for (int nf=0; nf<4; ++nf){
      #pragma unroll
      for (int c=0; c<2; ++c){
        short8 pf = *(const short8*)(&Ps[w][lr*72 + c*32 + lc*8]);
        short8 vf = *(const short8*)(&Vts[(nf*16+lr)*72 + c*32 + lc*8]);
        o[nf] = __builtin_amdgcn_mfma_f32_16x16x32_bf16(pf, vf, o[nf], 0,0,0);
      }
    }
  }
  #pragma unroll
  for (int nf=0; nf<4; ++nf)
    #pragma unroll
    for (int r=0; r<4; ++r){
      int qg = qt*64 + w*16 + lc*4 + r;
      attn_o[(size_t)(b*N_+qg)*1024 + h*64 + nf*16 + lr] = f2bf(o[nf][r] / l_run[r]);
    }
}

extern "C" void kernel_launch(void* const* d_in, const int* in_sizes, int n_in,
                              void* d_out, int out_size, void* d_ws, size_t ws_size,
                              hipStream_t stream){
  const float* x    = (const float*)d_in[0];
  const float* Wq   = (const float*)d_in[1];
  const float* Wkv  = (const float*)d_in[2];
  const float* Wkvh = (const float*)d_in[3];
  const float* Wo   = (const float*)d_in[4];
  float* out = (float*)d_out;

  char* p = (char*)d_ws;
  u16* xb      = (u16*)p;   p += (size_t)ROWS*1024*2;   // 8 MB (reused as attn_o later)
  u16* WqT     = (u16*)p;   p += (size_t)1024*1024*2;   // 2 MB
  u16* WoT     = (u16*)p;   p += (size_t)1024*1024*2;   // 2 MB
  u16* WkvT    = (u16*)p;   p += (size_t)192*1024*2;    // 384 KB
  float* q_raw = (float*)p; p += (size_t)ROWS*1024*4;   // 16 MB
  float* proj  = (float*)p; p += (size_t)ROWS*192*4;    // 3 MB
  u16* q_bf    = (u16*)p;   p += (size_t)ROWS*1024*2;   // 8 MB
  u16* k_rp    = (u16*)p;   p += (size_t)ROWS*64*2;     // 512 KB
  u16* v_bf    = (u16*)p;   p += (size_t)ROWS*64*2;     // 512 KB
  float* k_hd  = (float*)p; p += (size_t)ROWS*16*4;     // 256 KB
  float* v_hd  = (float*)p; p += (size_t)ROWS*16*4;     // 256 KB
  u16* attn_o  = xb;  // xb dead after the two projection GEMMs

  k_conv<<<ROWS*1024/4/256, 256, 0, stream>>>(x, xb);
  k_transpose1024<<<1024*1024/256, 256, 0, stream>>>(Wq, WqT);
  k_transpose1024<<<1024*1024/256, 256, 0, stream>>>(Wo, WoT);
  k_build_wkvt<<<192*1024/256, 256, 0, stream>>>(Wkv, Wkvh, WkvT);
  k_gemm_bt<<<(ROWS/64)*(1024/64), 256, 0, stream>>>(xb, WqT, q_raw, ROWS, 1024, 1024);
  k_gemm_bt<<<(ROWS/64)*(192/64),  256, 0, stream>>>(xb, WkvT, proj,  ROWS, 192, 1024);
  k_postproc<<<ROWS, 64, 0, stream>>>(proj, k_rp, v_bf, k_hd, v_hd);
  k_rope_q<<<ROWS*16*32/256, 256, 0, stream>>>(q_raw, q_bf);
  k_attn<<<B_*H_*(N_/64), 256, 0, stream>>>(q_bf, k_rp, v_bf, k_hd, v_hd, attn_o);
  k_gemm_bt<<<(ROWS/64)*(1024/64), 256, 0, stream>>>(attn_o, WoT, out, ROWS, 1024, 1024);
}

// Round 2
// 181.656 us; speedup vs baseline: 1.5395x; 1.5395x over previous
//
#include <hip/hip_runtime.h>

typedef unsigned short u16;
typedef unsigned int u32;
typedef __attribute__((ext_vector_type(8))) short short8;   // 8 bf16 (4 VGPRs) - MFMA A/B frag
typedef __attribute__((ext_vector_type(4))) float f32x4;    // MFMA C/D frag
typedef __attribute__((ext_vector_type(4))) u32 u32x4;      // 16B move
typedef __attribute__((ext_vector_type(4))) u16 u16x4;      // 8B move

constexpr int B_ = 2, N_ = 2048, H_ = 16;
constexpr int ROWS = B_ * N_;   // 4096

__device__ __forceinline__ float bf2f(u16 u){ union{u32 u; float f;} v; v.u = ((u32)u)<<16; return v.f; }
__device__ __forceinline__ u16 f2bf(float f){
  union{float f; u32 u;} v; v.f = f;
  u32 u = v.u; u += 0x7fffu + ((u>>16)&1u);   // RNE
  return (u16)(u>>16);
}

// ---- x fp32 -> bf16 (vectorized x4) ----
__global__ void k_conv(const float* __restrict__ x, u16* __restrict__ xb){
  int i = (blockIdx.x*blockDim.x + threadIdx.x)*4;
  f32x4 v = *(const f32x4*)(x + i);
  u16x4 o; o[0]=f2bf(v[0]); o[1]=f2bf(v[1]); o[2]=f2bf(v[2]); o[3]=f2bf(v[3]);
  *(u16x4*)(xb + i) = o;
}

// ---- W (1024x1024) -> W^T bf16 ----
__global__ void k_transpose1024(const float* __restrict__ in, u16* __restrict__ out){
  int idx = blockIdx.x*blockDim.x + threadIdx.x;   // over 1024*1024, out[n*1024+k]
  int n = idx >> 10, k = idx & 1023;
  out[idx] = f2bf(in[k*1024 + n]);
}

// ---- [Wkv | Wkvh | 0] concatenated transpose: out is (192 x 1024) bf16 ----
__global__ void k_build_wkvt(const float* __restrict__ Wkv, const float* __restrict__ Wkvh,
                             u16* __restrict__ out){
  int idx = blockIdx.x*blockDim.x + threadIdx.x;   // over 192*1024
  int n = idx >> 10, k = idx & 1023;
  float v = 0.f;
  if (n < 128)      v = Wkv[k*128 + n];
  else if (n < 160) v = Wkvh[k*32 + (n-128)];
  out[idx] = f2bf(v);
}

// ---- bf16 MFMA GEMM, 64x64 tile (kept for the skinny N=192 KV projection) ----
__global__ __launch_bounds__(256) void k_gemm_bt(const u16* __restrict__ A, const u16* __restrict__ Bt,
                                                 float* __restrict__ C, int M, int N, int K){
  __shared__ u16 As[64*72];
  __shared__ u16 Bs[64*72];
  int ntile = N >> 6;
  int m0 = (blockIdx.x / ntile) << 6;
  int n0 = (blockIdx.x % ntile) << 6;
  int tid = threadIdx.x;
  int w = tid >> 6, l = tid & 63, lr = l & 15, lc = l >> 4;
  int wm = (w >> 1) * 32, wn = (w & 1) * 32;
  f32x4 acc[2][2] = {};
  for (int kt = 0; kt < K; kt += 64){
    __syncthreads();
    #pragma unroll
    for (int s = 0; s < 2; ++s){
      int chunk = tid + s*256;
      int r = chunk >> 3, c8 = (chunk & 7) << 3;
      *(u32x4*)(&As[r*72 + c8]) = *(const u32x4*)(&A[(size_t)(m0 + r)*K + kt + c8]);
      *(u32x4*)(&Bs[r*72 + c8]) = *(const u32x4*)(&Bt[(size_t)(n0 + r)*K + kt + c8]);
    }
    __syncthreads();
    short8 af[2][2], bfr[2][2];
    #pragma unroll
    for (int mf=0; mf<2; ++mf)
      #pragma unroll
      for (int c=0; c<2; ++c)
        af[mf][c] = *(const short8*)(&As[(wm + mf*16 + lr)*72 + c*32 + lc*8]);
    #pragma unroll
    for (int nf=0; nf<2; ++nf)
      #pragma unroll
      for (int c=0; c<2; ++c)
        bfr[nf][c] = *(const short8*)(&Bs[(wn + nf*16 + lr)*72 + c*32 + lc*8]);
    #pragma unroll
    for (int mf=0; mf<2; ++mf)
      #pragma unroll
      for (int nf=0; nf<2; ++nf)
        #pragma unroll
        for (int c=0; c<2; ++c)
          acc[mf][nf] = __builtin_amdgcn_mfma_f32_16x16x32_bf16(af[mf][c], bfr[nf][c], acc[mf][nf], 0,0,0);
  }
  #pragma unroll
  for (int mf=0; mf<2; ++mf)
    #pragma unroll
    for (int nf=0; nf<2; ++nf)
      #pragma unroll
      for (int r=0; r<4; ++r)
        C[(size_t)(m0 + wm + mf*16 + lc*4 + r)*N + n0 + wn + nf*16 + lr] = acc[mf][nf][r];
}

// ---- m97-style 128x128 GEMM: global_load_lds width-16, linear LDS, 4 waves, 64x64 out/wave ----
__global__ __launch_bounds__(256) void k_gemm128(const u16* __restrict__ A, const u16* __restrict__ Bt,
                                                 float* __restrict__ C, int M, int N, int K){
  __shared__ u16 As[128*64];
  __shared__ u16 Bs[128*64];
  int ntile = N >> 7;
  int m0 = (blockIdx.x / ntile) << 7;
  int n0 = (blockIdx.x % ntile) << 7;
  int tid = threadIdx.x;
  int l = tid & 63, lr = l & 15, lc = l >> 4;
  int w = tid >> 6;
  int wm = (w >> 1) * 64, wn = (w & 1) * 64;
  int r_st = tid >> 3, c8_st = (tid & 7) << 3;       // staging coords for s=0
  f32x4 acc[4][4] = {};
  for (int kt = 0; kt < K; kt += 64){
    __syncthreads();
    #pragma unroll
    for (int s = 0; s < 4; ++s){
      int r = r_st + s*32;                           // chunk = s*256+tid; r = chunk>>3
      __builtin_amdgcn_global_load_lds(
        (const __attribute__((address_space(1))) u32*)(&A[(size_t)(m0 + r)*K + kt + c8_st]),
        (__attribute__((address_space(3))) u32*)(&As[r*64 + c8_st]), 16, 0, 0);
      __builtin_amdgcn_global_load_lds(
        (const __attribute__((address_space(1))) u32*)(&Bt[(size_t)(n0 + r)*K + kt + c8_st]),
        (__attribute__((address_space(3))) u32*)(&Bs[r*64 + c8_st]), 16, 0, 0);
    }
    __syncthreads();
    short8 af[4][2], bfr[4][2];
    #pragma unroll
    for (int m=0; m<4; ++m)
      #pragma unroll
      for (int c=0; c<2; ++c)
        af[m][c] = *(const short8*)(&As[(wm + m*16 + lr)*64 + c*32 + lc*8]);
    #pragma unroll
    for (int n=0; n<4; ++n)
      #pragma unroll
      for (int c=0; c<2; ++c)
        bfr[n][c] = *(const short8*)(&Bs[(wn + n*16 + lr)*64 + c*32 + lc*8]);
    #pragma unroll
    for (int m=0; m<4; ++m)
      #pragma unroll
      for (int n=0; n<4; ++n)
        #pragma unroll
        for (int c=0; c<2; ++c)
          acc[m][n] = __builtin_amdgcn_mfma_f32_16x16x32_bf16(af[m][c], bfr[n][c], acc[m][n], 0,0,0);
  }
  #pragma unroll
  for (int m=0; m<4; ++m)
    #pragma unroll
    for (int n=0; n<4; ++n)
      #pragma unroll
      for (int r=0; r<4; ++r)
        C[(size_t)(m0 + wm + m*16 + lc*4 + r)*N + n0 + wn + n*16 + lr] = acc[m][n][r];
}

// ---- proj (ROWS x 192) -> rope'd k_rope bf16, v bf16, sigmoid gates (b,h,N) fp32 ----
__global__ void k_postproc(const float* __restrict__ proj, u16* __restrict__ k_rope,
                           u16* __restrict__ v_bf, float* __restrict__ k_head,
                           float* __restrict__ v_head){
  int row = blockIdx.x;            // b*N + n
  int n = row & (N_-1);
  int b = row >> 11;
  int t = threadIdx.x;             // 64
  const float* p = proj + (size_t)row*192;
  v_bf[row*64 + t] = f2bf(p[64 + t]);
  if (t < 32){
    float hv = 1.f/(1.f + __expf(-p[128 + t]));
    if (t < 16) k_head[((size_t)b*16 + t)*N_ + n] = hv;
    else        v_head[((size_t)b*16 + (t-16))*N_ + n] = hv;
    float inv = powf(10000.f, -(float)t*(1.f/32.f));
    float ang = (float)n * inv;
    float sn = sinf(ang), cs = cosf(ang);
    float k1 = p[t], k2 = p[32 + t];
    k_rope[row*64 + t]      = f2bf(k1*cs - k2*sn);
    k_rope[row*64 + 32 + t] = f2bf(k2*cs + k1*sn);
  }
}

// ---- tiled transpose: v_bf (b,n,64) -> vt (b,64,N) ----
__global__ __launch_bounds__(256) void k_transp_v(const u16* __restrict__ v_bf, u16* __restrict__ vt){
  __shared__ u16 T[64*72];
  int b = blockIdx.x >> 5;
  int n0 = (blockIdx.x & 31) << 6;
  int tid = threadIdx.x;
  #pragma unroll
  for (int s=0; s<2; ++s){
    int chunk = tid + s*256, r = chunk>>3, c8 = (chunk&7)<<3;
    *(u32x4*)(&T[r*72 + c8]) = *(const u32x4*)(&v_bf[((size_t)b*N_ + n0 + r)*64 + c8]);
  }
  __syncthreads();
  #pragma unroll
  for (int s=0; s<2; ++s){
    int chunk = tid + s*256, d = chunk>>3, c8 = (chunk&7)<<3;
    u32x4 o; u16* op = (u16*)&o;
    #pragma unroll
    for (int j=0; j<8; ++j) op[j] = T[(c8+j)*72 + d];
    *(u32x4*)(&vt[((size_t)b*64 + d)*N_ + n0 + c8]) = o;
  }
}

// ---- q_raw fp32 -> rope + scale(0.125) -> q bf16 ----
__global__ void k_rope_q(const float* __restrict__ q_raw, u16* __restrict__ q_bf){
  int idx = blockIdx.x*blockDim.x + threadIdx.x;   // over ROWS*16*32
  int i = idx & 31;
  int h = (idx >> 5) & 15;
  int row = idx >> 9;
  int n = row & (N_-1);
  float inv = powf(10000.f, -(float)i*(1.f/32.f));
  float ang = (float)n * inv;
  float sn = sinf(ang), cs = cosf(ang);
  const float* q = q_raw + (size_t)row*1024 + h*64;
  u16* o = q_bf + (size_t)row*1024 + h*64;
  float x1 = q[i], x2 = q[i+32];
  o[i]    = f2bf(0.125f*(x1*cs - x2*sn));
  o[i+32] = f2bf(0.125f*(x2*cs + x1*sn));
}

// ---- flash attention v2: gates in registers, vectorized staging, 2 barriers/step, LPT dispatch ----
__global__ __launch_bounds__(256) void k_attn2(const u16* __restrict__ q_bf, const u16* __restrict__ k_rp,
                                               const u16* __restrict__ vt, const float* __restrict__ k_hd,
                                               const float* __restrict__ v_hd, u16* __restrict__ attn_o){
  __shared__ u16 Ks[64*72];      // [key][hd], raw bf16
  __shared__ u16 Vts[64*72];     // [hd][key], raw bf16 (from precomputed vt)
  __shared__ u16 Ps[4][16*72];   // per-wave P tile (wave-private)
  __shared__ float gk_s[64], gv_s[64];
  int z = blockIdx.x;
  int qt = 31 - (z >> 5);        // qt-major DESCENDING: 32-step blocks dispatch first
  int h = z & 15, b = (z >> 4) & 1;
  int tid = threadIdx.x, w = tid>>6, l = tid&63, lr = l&15, lc = l>>4;
  size_t rowbase = (size_t)b*N_;
  int qrow = qt*64 + w*16 + lr;
  size_t qoff = (rowbase + qrow)*1024 + h*64;
  short8 qf0 = *(const short8*)(&q_bf[qoff + lc*8]);
  short8 qf1 = *(const short8*)(&q_bf[qoff + 32 + lc*8]);
  const float* gkp = k_hd + ((size_t)b*16 + h)*N_;
  const float* gvp = v_hd + ((size_t)b*16 + h)*N_;
  float m_run[4] = {-1e30f,-1e30f,-1e30f,-1e30f};
  float l_run[4] = {0.f,0.f,0.f,0.f};
  f32x4 o[4] = {};
  for (int kt = 0; kt <= qt; ++kt){
    int kg0 = kt*64;
    __syncthreads();                       // prior-step PV reads done before restage
    #pragma unroll
    for (int s=0; s<2; ++s){
      int chunk = tid + s*256, r = chunk>>3, c8 = (chunk&7)<<3;
      *(u32x4*)(&Ks[r*72 + c8])  = *(const u32x4*)(&k_rp[(rowbase + kg0 + r)*64 + c8]);
      *(u32x4*)(&Vts[r*72 + c8]) = *(const u32x4*)(&vt[((size_t)b*64 + r)*N_ + kg0 + c8]);
    }
    if (tid < 64)       gk_s[tid]     = gkp[kg0 + tid];
    else if (tid < 128) gv_s[tid-64]  = gvp[kg0 + tid - 64];
    __syncthreads();
    // S = Q * K^T  (16q x 64k per wave)
    f32x4 s4[4] = {};
    #pragma unroll
    for (int nf=0; nf<4; ++nf){
      short8 kf0 = *(const short8*)(&Ks[(nf*16+lr)*72 + lc*8]);
      short8 kf1 = *(const short8*)(&Ks[(nf*16+lr)*72 + 32 + lc*8]);
      s4[nf] = __builtin_amdgcn_mfma_f32_16x16x32_bf16(qf0, kf0, s4[nf], 0,0,0);
      s4[nf] = __builtin_amdgcn_mfma_f32_16x16x32_bf16(qf1, kf1, s4[nf], 0,0,0);
    }
    // column gates (k_head) in registers
    float gk4[4], gv4[4];
    #pragma unroll
    for (int nf=0; nf<4; ++nf){ gk4[nf] = gk_s[nf*16+lr]; gv4[nf] = gv_s[nf*16+lr]; }
    #pragma unroll
    for (int nf=0; nf<4; ++nf)
      #pragma unroll
      for (int r=0; r<4; ++r) s4[nf][r] *= gk4[nf];
    if (kt == qt){
      #pragma unroll
      for (int nf=0; nf<4; ++nf)
        #pragma unroll
        for (int r=0; r<4; ++r){
          int kcol = kg0 + nf*16 + lr;
          int qg   = qt*64 + w*16 + lc*4 + r;
          if (kcol > qg) s4[nf][r] = -1e30f;
        }
    }
    // online softmax (rows live across 16 consecutive lanes)
    float rm[4], al[4], ps[4];
    #pragma unroll
    for (int r=0; r<4; ++r) rm[r] = fmaxf(fmaxf(s4[0][r], s4[1][r]), fmaxf(s4[2][r], s4[3][r]));
    #pragma unroll
    for (int mk=1; mk<16; mk<<=1)
      #pragma unroll
      for (int r=0; r<4; ++r) rm[r] = fmaxf(rm[r], __shfl_xor(rm[r], mk));
    #pragma unroll
    for (int r=0; r<4; ++r){
      float mn = fmaxf(m_run[r], rm[r]);
      al[r] = __expf(m_run[r] - mn);
      m_run[r] = mn;
    }
    #pragma unroll
    for (int nf=0; nf<4; ++nf)
      #pragma unroll
      for (int r=0; r<4; ++r) s4[nf][r] = __expf(s4[nf][r] - m_run[r]);
    #pragma unroll
    for (int r=0; r<4; ++r) ps[r] = s4[0][r]+s4[1][r]+s4[2][r]+s4[3][r];
    #pragma unroll
    for (int mk=1; mk<16; mk<<=1)
      #pragma unroll
      for (int r=0; r<4; ++r) ps[r] += __shfl_xor(ps[r], mk);
    #pragma unroll
    for (int r=0; r<4; ++r) l_run[r] = l_run[r]*al[r] + ps[r];
    // fold v_head gate into P, write wave-private P tile
    #pragma unroll
    for (int nf=0; nf<4; ++nf)
      #pragma unroll
      for (int r=0; r<4; ++r){
        o[nf][r] *= al[r];
        Ps[w][(lc*4+r)*72 + nf*16 + lr] = f2bf(s4[nf][r] * gv4[nf]);
      }
    asm volatile("s_waitcnt lgkmcnt(0)" ::: "memory");   // wave-private P: no barrier needed
    __builtin_amdgcn_sched_barrier(0);
    // O += P * V   (P rows are A-frags; Vts rows d are B-frags)
    short8 pf0 = *(const short8*)(&Ps[w][lr*72 + lc*8]);
    short8 pf1 = *(const short8*)(&Ps[w][lr*72 + 32 + lc*8]);
    #pragma unroll
    for (int nf=0; nf<4; ++nf){
      short8 vf0 = *(const short8*)(&Vts[(nf*16+lr)*72 + lc*8]);
      short8 vf1 = *(const short8*)(&Vts[(nf*16+lr)*72 + 32 + lc*8]);
      o[nf] = __builtin_amdgcn_mfma_f32_16x16x32_bf16(pf0, vf0, o[nf], 0,0,0);
      o[nf] = __builtin_amdgcn_mfma_f32_16x16x32_bf16(pf1, vf1, o[nf], 0,0,0);
    }
  }
  #pragma unroll
  for (int nf=0; nf<4; ++nf)
    #pragma unroll
    for (int r=0; r<4; ++r){
      int qg = qt*64 + w*16 + lc*4 + r;
      attn_o[(size_t)(b*N_+qg)*1024 + h*64 + nf*16 + lr] = f2bf(o[nf][r] / l_run[r]);
    }
}

extern "C" void kernel_launch(void* const* d_in, const int* in_sizes, int n_in,
                              void* d_out, int out_size, void* d_ws, size_t ws_size,
                              hipStream_t stream){
  const float* x    = (const float*)d_in[0];
  const float* Wq   = (const float*)d_in[1];
  const float* Wkv  = (const float*)d_in[2];
  const float* Wkvh = (const float*)d_in[3];
  const float* Wo   = (const float*)d_in[4];
  float* out = (float*)d_out;

  char* p = (char*)d_ws;
  u16* xb      = (u16*)p;   p += (size_t)ROWS*1024*2;   // 8 MB (reused as attn_o later)
  u16* WqT     = (u16*)p;   p += (size_t)1024*1024*2;   // 2 MB
  u16* WoT     = (u16*)p;   p += (size_t)1024*1024*2;   // 2 MB
  u16* WkvT    = (u16*)p;   p += (size_t)192*1024*2;    // 384 KB
  float* q_raw = (float*)p; p += (size_t)ROWS*1024*4;   // 16 MB
  float* proj  = (float*)p; p += (size_t)ROWS*192*4;    // 3 MB
  u16* q_bf    = (u16*)p;   p += (size_t)ROWS*1024*2;   // 8 MB
  u16* k_rp    = (u16*)p;   p += (size_t)ROWS*64*2;     // 512 KB
  u16* v_bf    = (u16*)p;   p += (size_t)ROWS*64*2;     // 512 KB
  u16* vt      = (u16*)p;   p += (size_t)B_*64*N_*2;    // 512 KB (b,64,N)
  float* k_hd  = (float*)p; p += (size_t)B_*H_*N_*4;    // 256 KB (b,h,N)
  float* v_hd  = (float*)p; p += (size_t)B_*H_*N_*4;    // 256 KB (b,h,N)
  u16* attn_o  = xb;  // xb dead after the two projection GEMMs

  k_conv<<<ROWS*1024/4/256, 256, 0, stream>>>(x, xb);
  k_transpose1024<<<1024*1024/256, 256, 0, stream>>>(Wq, WqT);
  k_transpose1024<<<1024*1024/256, 256, 0, stream>>>(Wo, WoT);
  k_build_wkvt<<<192*1024/256, 256, 0, stream>>>(Wkv, Wkvh, WkvT);
  k_gemm128<<<(ROWS/128)*(1024/128), 256, 0, stream>>>(xb, WqT, q_raw, ROWS, 1024, 1024);
  k_gemm_bt<<<(ROWS/64)*(192/64),  256, 0, stream>>>(xb, WkvT, proj,  ROWS, 192, 1024);
  k_postproc<<<ROWS, 64, 0, stream>>>(proj, k_rp, v_bf, k_hd, v_hd);
  k_transp_v<<<B_*(N_/64), 256, 0, stream>>>(v_bf, vt);
  k_rope_q<<<ROWS*16*32/256, 256, 0, stream>>>(q_raw, q_bf);
  k_attn2<<<B_*H_*(N_/64), 256, 0, stream>>>(q_bf, k_rp, vt, k_hd, v_hd, attn_o);
  k_gemm128<<<(ROWS/128)*(1024/128), 256, 0, stream>>>(attn_o, WoT, out, ROWS, 1024, 1024);
}

// Round 3
// 157.576 us; speedup vs baseline: 1.7748x; 1.1528x over previous
//
#include <hip/hip_runtime.h>

typedef unsigned short u16;
typedef unsigned int u32;
typedef __attribute__((ext_vector_type(8))) short short8;   // 8 bf16 (4 VGPRs) - MFMA A/B frag
typedef __attribute__((ext_vector_type(4))) float f32x4;    // MFMA C/D frag
typedef __attribute__((ext_vector_type(4))) u32 u32x4;      // 16B move
typedef __attribute__((ext_vector_type(2))) u32 u32x2;      // 8B move
typedef __attribute__((ext_vector_type(4))) u16 u16x4;      // 8B move

constexpr int B_ = 2, N_ = 2048, H_ = 16;
constexpr int ROWS = B_ * N_;   // 4096
constexpr float LOG2E = 1.44269504088896f;

__device__ __forceinline__ float bf2f(u16 u){ union{u32 u; float f;} v; v.u = ((u32)u)<<16; return v.f; }
__device__ __forceinline__ u16 f2bf(float f){
  union{float f; u32 u;} v; v.f = f;
  u32 u = v.u; u += 0x7fffu + ((u>>16)&1u);   // RNE
  return (u16)(u>>16);
}
__device__ __forceinline__ u32 cvtpk(float lo, float hi){
  u32 r; asm("v_cvt_pk_bf16_f32 %0, %1, %2" : "=v"(r) : "v"(lo), "v"(hi)); return r;
}

// ---- x fp32 -> bf16 (vectorized x4) ----
__global__ void k_conv(const float* __restrict__ x, u16* __restrict__ xb){
  int i = (blockIdx.x*blockDim.x + threadIdx.x)*4;
  f32x4 v = *(const f32x4*)(x + i);
  u16x4 o; o[0]=f2bf(v[0]); o[1]=f2bf(v[1]); o[2]=f2bf(v[2]); o[3]=f2bf(v[3]);
  *(u16x4*)(xb + i) = o;
}

// ---- rope trig table: tab[n*32+i] = (cos, sin) of n * 10000^(-i/32) ----
__global__ void k_trig(float2* __restrict__ tab){
  int idx = blockIdx.x*blockDim.x + threadIdx.x;   // N_*32
  int i = idx & 31, n = idx >> 5;
  float ang = (float)n * exp2f(-(float)i * 0.4152410118609203f);  // log2(10000)/32
  tab[idx] = make_float2(cosf(ang), sinf(ang));
}

// ---- LDS-tiled transpose: in (1024x1024 fp32) -> out (1024x1024 bf16, transposed) ----
__global__ __launch_bounds__(256) void k_transpose_t(const float* __restrict__ in, u16* __restrict__ out){
  __shared__ float T[64*65];
  int n0 = (blockIdx.x & 15) << 6, k0 = (blockIdx.x >> 4) << 6;
  int tid = threadIdx.x;
  #pragma unroll
  for (int s=0; s<4; ++s){
    int chunk = tid + s*256, r = chunk >> 4, c4 = (chunk & 15) << 2;
    *(f32x4*)(&T[r*65 + c4]) = *(const f32x4*)(&in[(size_t)(k0 + r)*1024 + n0 + c4]);
  }
  __syncthreads();
  #pragma unroll
  for (int s=0; s<2; ++s){
    int chunk = tid + s*256, d = chunk >> 3, c8 = (chunk & 7) << 3;
    u16x4 o1, o2;
    #pragma unroll
    for (int j=0; j<4; ++j){ o1[j] = f2bf(T[(c8+j)*65 + d]); o2[j] = f2bf(T[(c8+4+j)*65 + d]); }
    *(u16x4*)(&out[(size_t)(n0 + d)*1024 + k0 + c8])     = o1;
    *(u16x4*)(&out[(size_t)(n0 + d)*1024 + k0 + c8 + 4]) = o2;
  }
}

// ---- [Wkv | Wkvh | 0] concatenated transpose: out is (192 x 1024) bf16 ----
__global__ void k_build_wkvt(const float* __restrict__ Wkv, const float* __restrict__ Wkvh,
                             u16* __restrict__ out){
  int idx = blockIdx.x*blockDim.x + threadIdx.x;   // over 192*1024
  int n = idx >> 10, k = idx & 1023;
  float v = 0.f;
  if (n < 128)      v = Wkv[k*128 + n];
  else if (n < 160) v = Wkvh[k*32 + (n-128)];
  out[idx] = f2bf(v);
}

// ---- bf16 MFMA GEMM, 64x64 tile (kept for the skinny N=192 KV projection) ----
__global__ __launch_bounds__(256) void k_gemm_bt(const u16* __restrict__ A, const u16* __restrict__ Bt,
                                                 float* __restrict__ C, int M, int N, int K){
  __shared__ u16 As[64*72];
  __shared__ u16 Bs[64*72];
  int ntile = N >> 6;
  int m0 = (blockIdx.x / ntile) << 6;
  int n0 = (blockIdx.x % ntile) << 6;
  int tid = threadIdx.x;
  int w = tid >> 6, l = tid & 63, lr = l & 15, lc = l >> 4;
  int wm = (w >> 1) * 32, wn = (w & 1) * 32;
  f32x4 acc[2][2] = {};
  for (int kt = 0; kt < K; kt += 64){
    __syncthreads();
    #pragma unroll
    for (int s = 0; s < 2; ++s){
      int chunk = tid + s*256;
      int r = chunk >> 3, c8 = (chunk & 7) << 3;
      *(u32x4*)(&As[r*72 + c8]) = *(const u32x4*)(&A[(size_t)(m0 + r)*K + kt + c8]);
      *(u32x4*)(&Bs[r*72 + c8]) = *(const u32x4*)(&Bt[(size_t)(n0 + r)*K + kt + c8]);
    }
    __syncthreads();
    short8 af[2][2], bfr[2][2];
    #pragma unroll
    for (int mf=0; mf<2; ++mf)
      #pragma unroll
      for (int c=0; c<2; ++c)
        af[mf][c] = *(const short8*)(&As[(wm + mf*16 + lr)*72 + c*32 + lc*8]);
    #pragma unroll
    for (int nf=0; nf<2; ++nf)
      #pragma unroll
      for (int c=0; c<2; ++c)
        bfr[nf][c] = *(const short8*)(&Bs[(wn + nf*16 + lr)*72 + c*32 + lc*8]);
    #pragma unroll
    for (int mf=0; mf<2; ++mf)
      #pragma unroll
      for (int nf=0; nf<2; ++nf)
        #pragma unroll
        for (int c=0; c<2; ++c)
          acc[mf][nf] = __builtin_amdgcn_mfma_f32_16x16x32_bf16(af[mf][c], bfr[nf][c], acc[mf][nf], 0,0,0);
  }
  #pragma unroll
  for (int mf=0; mf<2; ++mf)
    #pragma unroll
    for (int nf=0; nf<2; ++nf)
      #pragma unroll
      for (int r=0; r<4; ++r)
        C[(size_t)(m0 + wm + mf*16 + lc*4 + r)*N + n0 + wn + nf*16 + lr] = acc[mf][nf][r];
}

// ---- m97-style 128x128 GEMM. MODE 0: fp32 out. MODE 1: fused rope+scale -> bf16 out (q path) ----
template<int MODE>
__global__ __launch_bounds__(256) void k_gemm128(const u16* __restrict__ A, const u16* __restrict__ Bt,
                                                 void* __restrict__ Cv, const float2* __restrict__ tab,
                                                 int M, int N, int K){
  __shared__ u16 As[128*64];
  __shared__ u16 Bs[128*64];
  int ntile = N >> 7;
  int m0 = (blockIdx.x / ntile) << 7;
  int n0 = (blockIdx.x % ntile) << 7;
  int tid = threadIdx.x;
  int l = tid & 63, lr = l & 15, lc = l >> 4;
  int w = tid >> 6;
  int wm = (w >> 1) * 64, wn = (w & 1) * 64;
  int r_st = tid >> 3, c8_st = (tid & 7) << 3;
  f32x4 acc[4][4] = {};
  for (int kt = 0; kt < K; kt += 64){
    __syncthreads();
    #pragma unroll
    for (int s = 0; s < 4; ++s){
      int r = r_st + s*32;
      __builtin_amdgcn_global_load_lds(
        (const __attribute__((address_space(1))) u32*)(&A[(size_t)(m0 + r)*K + kt + c8_st]),
        (__attribute__((address_space(3))) u32*)(&As[r*64 + c8_st]), 16, 0, 0);
      __builtin_amdgcn_global_load_lds(
        (const __attribute__((address_space(1))) u32*)(&Bt[(size_t)(n0 + r)*K + kt + c8_st]),
        (__attribute__((address_space(3))) u32*)(&Bs[r*64 + c8_st]), 16, 0, 0);
    }
    __syncthreads();
    short8 af[4][2], bfr[4][2];
    #pragma unroll
    for (int m=0; m<4; ++m)
      #pragma unroll
      for (int c=0; c<2; ++c)
        af[m][c] = *(const short8*)(&As[(wm + m*16 + lr)*64 + c*32 + lc*8]);
    #pragma unroll
    for (int n=0; n<4; ++n)
      #pragma unroll
      for (int c=0; c<2; ++c)
        bfr[n][c] = *(const short8*)(&Bs[(wn + n*16 + lr)*64 + c*32 + lc*8]);
    #pragma unroll
    for (int m=0; m<4; ++m)
      #pragma unroll
      for (int n=0; n<4; ++n)
        #pragma unroll
        for (int c=0; c<2; ++c)
          acc[m][n] = __builtin_amdgcn_mfma_f32_16x16x32_bf16(af[m][c], bfr[n][c], acc[m][n], 0,0,0);
  }
  if constexpr (MODE == 0){
    float* C = (float*)Cv;
    #pragma unroll
    for (int m=0; m<4; ++m)
      #pragma unroll
      for (int n=0; n<4; ++n)
        #pragma unroll
        for (int r=0; r<4; ++r)
          C[(size_t)(m0 + wm + m*16 + lc*4 + r)*N + n0 + wn + n*16 + lr] = acc[m][n][r];
  } else {
    // fused rope: cols within each 64-head: i = nf*16+lr (nf<2), partner i+32 lives in acc[m][nf+2]
    u16* C = (u16*)Cv;
    #pragma unroll
    for (int m=0; m<4; ++m){
      int grow = m0 + wm + m*16 + lc*4;
      #pragma unroll
      for (int nf=0; nf<2; ++nf){
        int i = nf*16 + lr;
        #pragma unroll
        for (int r=0; r<4; ++r){
          float2 cs = tab[(size_t)((grow + r) & (N_-1))*32 + i];
          float x1 = acc[m][nf][r], x2 = acc[m][nf+2][r];
          C[(size_t)(grow + r)*N + n0 + wn + i]      = f2bf(0.125f*(x1*cs.x - x2*cs.y));
          C[(size_t)(grow + r)*N + n0 + wn + i + 32] = f2bf(0.125f*(x2*cs.x + x1*cs.y));
        }
      }
    }
  }
}

// ---- proj (ROWS x 192) -> rope'd k_rope bf16, v bf16, gates (b,h,N) fp32 (k-gate has log2e folded) ----
__global__ void k_postproc(const float* __restrict__ proj, const float2* __restrict__ tab,
                           u16* __restrict__ k_rope, u16* __restrict__ v_bf,
                           float* __restrict__ k_head, float* __restrict__ v_head){
  int row = blockIdx.x;            // b*N + n
  int n = row & (N_-1);
  int b = row >> 11;
  int t = threadIdx.x;             // 64
  const float* p = proj + (size_t)row*192;
  v_bf[row*64 + t] = f2bf(p[64 + t]);
  if (t < 32){
    float hv = 1.f/(1.f + __expf(-p[128 + t]));
    if (t < 16) k_head[((size_t)b*16 + t)*N_ + n] = hv * LOG2E;   // log2e folded for exp2 softmax
    else        v_head[((size_t)b*16 + (t-16))*N_ + n] = hv;
    float2 cs = tab[n*32 + t];
    float k1 = p[t], k2 = p[32 + t];
    k_rope[row*64 + t]      = f2bf(k1*cs.x - k2*cs.y);
    k_rope[row*64 + 32 + t] = f2bf(k2*cs.x + k1*cs.y);
  }
}

// ---- tiled transpose: v_bf (b,n,64) -> vt (b,64,N) ----
__global__ __launch_bounds__(256) void k_transp_v(const u16* __restrict__ v_bf, u16* __restrict__ vt){
  __shared__ u16 T[64*72];
  int b = blockIdx.x >> 5;
  int n0 = (blockIdx.x & 31) << 6;
  int tid = threadIdx.x;
  #pragma unroll
  for (int s=0; s<2; ++s){
    int chunk = tid + s*256, r = chunk>>3, c8 = (chunk&7)<<3;
    *(u32x4*)(&T[r*72 + c8]) = *(const u32x4*)(&v_bf[((size_t)b*N_ + n0 + r)*64 + c8]);
  }
  __syncthreads();
  #pragma unroll
  for (int s=0; s<2; ++s){
    int chunk = tid + s*256, d = chunk>>3, c8 = (chunk&7)<<3;
    u32x4 o; u16* op = (u16*)&o;
    #pragma unroll
    for (int j=0; j<8; ++j) op[j] = T[(c8+j)*72 + d];
    *(u32x4*)(&vt[((size_t)b*64 + d)*N_ + n0 + c8]) = o;
  }
}

// ---- flash attention v3: swapped QK^T (S^T), scalar-per-lane softmax, exp2, packed P,
//      qt-pairing (qta=p, qtb=31-p) for perfect load balance + shared staging ----
__global__ __launch_bounds__(256, 2) void k_attn3(const u16* __restrict__ q_bf, const u16* __restrict__ k_rp,
                                                  const u16* __restrict__ vt, const float* __restrict__ k_hd,
                                                  const float* __restrict__ v_hd, u16* __restrict__ attn_o){
  __shared__ u16 Ks[64*72];      // [key][hd]
  __shared__ u16 Vts[64*72];     // [hd][key]
  __shared__ u16 Ps[4][16*72];   // per-wave P tile [q][k]
  __shared__ float al_s[4][16];  // per-wave al / l transport
  __shared__ float gk_s[64], gv_s[64];
  int z = blockIdx.x;
  int h = z & 15, pidx = (z >> 4) & 15, b = z >> 8;
  int qta = pidx, qtb = 31 - pidx;
  int tid = threadIdx.x, w = tid>>6, l = tid&63, lr = l&15, lc = l>>4;
  size_t rowbase = (size_t)b*N_;
  size_t qoff_a = (rowbase + qta*64 + w*16 + lr)*1024 + h*64;
  size_t qoff_b = (rowbase + qtb*64 + w*16 + lr)*1024 + h*64;
  short8 qa0 = *(const short8*)(&q_bf[qoff_a + lc*8]);
  short8 qa1 = *(const short8*)(&q_bf[qoff_a + 32 + lc*8]);
  short8 qb0 = *(const short8*)(&q_bf[qoff_b + lc*8]);
  short8 qb1 = *(const short8*)(&q_bf[qoff_b + 32 + lc*8]);
  const float* gkp = k_hd + ((size_t)b*16 + h)*N_;
  const float* gvp = v_hd + ((size_t)b*16 + h)*N_;
  float ma = -1e30f, la = 0.f, mb = -1e30f, lb = 0.f;
  f32x4 oa[4] = {}, ob[4] = {};
  for (int kt = 0; kt <= qtb; ++kt){
    int kg0 = kt*64;
    __syncthreads();                       // prior-step LDS reads done before restage
    #pragma unroll
    for (int s=0; s<2; ++s){
      int chunk = tid + s*256, r = chunk>>3, c8 = (chunk&7)<<3;
      *(u32x4*)(&Ks[r*72 + c8])  = *(const u32x4*)(&k_rp[(rowbase + kg0 + r)*64 + c8]);
      *(u32x4*)(&Vts[r*72 + c8]) = *(const u32x4*)(&vt[((size_t)b*64 + r)*N_ + kg0 + c8]);
    }
    if (tid < 64)       gk_s[tid]    = gkp[kg0 + tid];
    else if (tid < 128) gv_s[tid-64] = gvp[kg0 + tid - 64];
    __syncthreads();
    // tile-independent loads, shared by both q-tiles
    short8 kf[4][2];
    f32x4 gkv[4], gvv[4];
    #pragma unroll
    for (int nf=0; nf<4; ++nf){
      kf[nf][0] = *(const short8*)(&Ks[(nf*16+lr)*72 + lc*8]);
      kf[nf][1] = *(const short8*)(&Ks[(nf*16+lr)*72 + 32 + lc*8]);
      gkv[nf] = *(const f32x4*)(&gk_s[nf*16 + lc*4]);
      gvv[nf] = *(const f32x4*)(&gv_s[nf*16 + lc*4]);
    }
    auto process = [&](short8 q0, short8 q1, f32x4 (&o)[4], float& mR, float& lR, int qtt){
      // S^T = K * Q^T : lane holds q-row (lr), 16 k-values (kcol = nf*16 + lc*4 + r)
      f32x4 s4[4] = {};
      #pragma unroll
      for (int nf=0; nf<4; ++nf){
        s4[nf] = __builtin_amdgcn_mfma_f32_16x16x32_bf16(kf[nf][0], q0, s4[nf], 0,0,0);
        s4[nf] = __builtin_amdgcn_mfma_f32_16x16x32_bf16(kf[nf][1], q1, s4[nf], 0,0,0);
      }
      #pragma unroll
      for (int nf=0; nf<4; ++nf)
        #pragma unroll
        for (int r=0; r<4; ++r) s4[nf][r] *= gkv[nf][r];
      if (kt == qtt){
        int qg = qtt*64 + w*16 + lr;
        #pragma unroll
        for (int nf=0; nf<4; ++nf)
          #pragma unroll
          for (int r=0; r<4; ++r)
            if (kg0 + nf*16 + lc*4 + r > qg) s4[nf][r] = -1e30f;
      }
      float rm = -1e30f;
      #pragma unroll
      for (int nf=0; nf<4; ++nf)
        #pragma unroll
        for (int r=0; r<4; ++r) rm = fmaxf(rm, s4[nf][r]);
      rm = fmaxf(rm, __shfl_xor(rm, 16));
      rm = fmaxf(rm, __shfl_xor(rm, 32));
      float mn = fmaxf(mR, rm);
      float al = exp2f(mR - mn);
      mR = mn;
      float ps = 0.f;
      #pragma unroll
      for (int nf=0; nf<4; ++nf)
        #pragma unroll
        for (int r=0; r<4; ++r){ s4[nf][r] = exp2f(s4[nf][r] - mn); ps += s4[nf][r]; }
      ps += __shfl_xor(ps, 16);
      ps += __shfl_xor(ps, 32);
      lR = lR*al + ps;
      if (lc == 0) al_s[w][lr] = al;
      #pragma unroll
      for (int nf=0; nf<4; ++nf){
        u32 lo = cvtpk(s4[nf][0]*gvv[nf][0], s4[nf][1]*gvv[nf][1]);
        u32 hi = cvtpk(s4[nf][2]*gvv[nf][2], s4[nf][3]*gvv[nf][3]);
        *(u32x2*)(&Ps[w][lr*72 + nf*16 + lc*4]) = (u32x2){lo, hi};
      }
      asm volatile("s_waitcnt lgkmcnt(0)" ::: "memory");
      __builtin_amdgcn_sched_barrier(0);
      f32x4 alv = *(const f32x4*)(&al_s[w][lc*4]);
      short8 pf0 = *(const short8*)(&Ps[w][lr*72 + lc*8]);
      short8 pf1 = *(const short8*)(&Ps[w][lr*72 + 32 + lc*8]);
      #pragma unroll
      for (int nf=0; nf<4; ++nf){
        short8 vf0 = *(const short8*)(&Vts[(nf*16+lr)*72 + lc*8]);
        short8 vf1 = *(const short8*)(&Vts[(nf*16+lr)*72 + 32 + lc*8]);
        #pragma unroll
        for (int r=0; r<4; ++r) o[nf][r] *= alv[r];
        o[nf] = __builtin_amdgcn_mfma_f32_16x16x32_bf16(pf0, vf0, o[nf], 0,0,0);
        o[nf] = __builtin_amdgcn_mfma_f32_16x16x32_bf16(pf1, vf1, o[nf], 0,0,0);
      }
    };
    process(qb0, qb1, ob, mb, lb, qtb);
    if (kt <= qta) process(qa0, qa1, oa, ma, la, qta);
  }
  // epilogue: transport l into o-layout, normalize, store (o: row q = lc*4+r, col d = nf*16+lr)
  auto store_tile = [&](f32x4 (&o)[4], float lR, int qtt){
    if (lc == 0) al_s[w][lr] = lR;
    asm volatile("s_waitcnt lgkmcnt(0)" ::: "memory");
    __builtin_amdgcn_sched_barrier(0);
    f32x4 lv = *(const f32x4*)(&al_s[w][lc*4]);
    #pragma unroll
    for (int nf=0; nf<4; ++nf)
      #pragma unroll
      for (int r=0; r<4; ++r)
        attn_o[(rowbase + qtt*64 + w*16 + lc*4 + r)*1024 + h*64 + nf*16 + lr] = f2bf(o[nf][r] / lv[r]);
  };
  store_tile(ob, lb, qtb);
  store_tile(oa, la, qta);
}

extern "C" void kernel_launch(void* const* d_in, const int* in_sizes, int n_in,
                              void* d_out, int out_size, void* d_ws, size_t ws_size,
                              hipStream_t stream){
  const float* x    = (const float*)d_in[0];
  const float* Wq   = (const float*)d_in[1];
  const float* Wkv  = (const float*)d_in[2];
  const float* Wkvh = (const float*)d_in[3];
  const float* Wo   = (const float*)d_in[4];
  float* out = (float*)d_out;

  char* p = (char*)d_ws;
  u16* xb      = (u16*)p;   p += (size_t)ROWS*1024*2;   // 8 MB (reused as attn_o later)
  u16* WqT     = (u16*)p;   p += (size_t)1024*1024*2;   // 2 MB
  u16* WoT     = (u16*)p;   p += (size_t)1024*1024*2;   // 2 MB
  u16* WkvT    = (u16*)p;   p += (size_t)192*1024*2;    // 384 KB
  float* proj  = (float*)p; p += (size_t)ROWS*192*4;    // 3 MB
  u16* q_bf    = (u16*)p;   p += (size_t)ROWS*1024*2;   // 8 MB
  u16* k_rp    = (u16*)p;   p += (size_t)ROWS*64*2;     // 512 KB
  u16* v_bf    = (u16*)p;   p += (size_t)ROWS*64*2;     // 512 KB
  u16* vt      = (u16*)p;   p += (size_t)B_*64*N_*2;    // 512 KB (b,64,N)
  float* k_hd  = (float*)p; p += (size_t)B_*H_*N_*4;    // 256 KB (b,h,N), log2e folded
  float* v_hd  = (float*)p; p += (size_t)B_*H_*N_*4;    // 256 KB (b,h,N)
  float2* tab  = (float2*)p; p += (size_t)N_*32*8;      // 512 KB rope trig
  u16* attn_o  = xb;  // xb dead after the two projection GEMMs

  k_conv<<<ROWS*1024/4/256, 256, 0, stream>>>(x, xb);
  k_trig<<<N_*32/256, 256, 0, stream>>>(tab);
  k_transpose_t<<<256, 256, 0, stream>>>(Wq, WqT);
  k_transpose_t<<<256, 256, 0, stream>>>(Wo, WoT);
  k_build_wkvt<<<192*1024/256, 256, 0, stream>>>(Wkv, Wkvh, WkvT);
  k_gemm128<1><<<(ROWS/128)*(1024/128), 256, 0, stream>>>(xb, WqT, q_bf, tab, ROWS, 1024, 1024);
  k_gemm_bt<<<(ROWS/64)*(192/64), 256, 0, stream>>>(xb, WkvT, proj, ROWS, 192, 1024);
  k_postproc<<<ROWS, 64, 0, stream>>>(proj, tab, k_rp, v_bf, k_hd, v_hd);
  k_transp_v<<<B_*(N_/64), 256, 0, stream>>>(v_bf, vt);
  k_attn3<<<B_*H_*16, 256, 0, stream>>>(q_bf, k_rp, vt, k_hd, v_hd, attn_o);
  k_gemm128<0><<<(ROWS/128)*(1024/128), 256, 0, stream>>>(attn_o, WoT, out, nullptr, ROWS, 1024, 1024);
}

// Round 4
// 153.280 us; speedup vs baseline: 1.8245x; 1.0280x over previous
//
#include <hip/hip_runtime.h>

typedef unsigned short u16;
typedef unsigned int u32;
typedef __attribute__((ext_vector_type(8))) short short8;   // 8 bf16 (4 VGPRs) - MFMA A/B frag
typedef __attribute__((ext_vector_type(4))) float f32x4;    // MFMA C/D frag
typedef __attribute__((ext_vector_type(4))) u32 u32x4;      // 16B move
typedef __attribute__((ext_vector_type(2))) u32 u32x2;      // 8B move
typedef __attribute__((ext_vector_type(4))) u16 u16x4;      // 8B move

constexpr int B_ = 2, N_ = 2048, H_ = 16;
constexpr int ROWS = B_ * N_;   // 4096
constexpr float LOG2E = 1.44269504088896f;

__device__ __forceinline__ float bf2f(u16 u){ union{u32 u; float f;} v; v.u = ((u32)u)<<16; return v.f; }
__device__ __forceinline__ u16 f2bf(float f){
  union{float f; u32 u;} v; v.f = f;
  u32 u = v.u; u += 0x7fffu + ((u>>16)&1u);   // RNE
  return (u16)(u>>16);
}
__device__ __forceinline__ u32 cvtpk(float lo, float hi){
  u32 r; asm("v_cvt_pk_bf16_f32 %0, %1, %2" : "=v"(r) : "v"(lo), "v"(hi)); return r;
}

// ---- fused: x fp32 -> bf16 (blocks 0..4095)  |  rope trig table (blocks 4096..4351) ----
__global__ void k_prep(const float* __restrict__ x, u16* __restrict__ xb, float2* __restrict__ tab){
  int bid = blockIdx.x;
  if (bid < 4096){
    int i = (bid*256 + threadIdx.x)*4;
    f32x4 v = *(const f32x4*)(x + i);
    u16x4 o; o[0]=f2bf(v[0]); o[1]=f2bf(v[1]); o[2]=f2bf(v[2]); o[3]=f2bf(v[3]);
    *(u16x4*)(xb + i) = o;
  } else {
    int idx = (bid-4096)*256 + threadIdx.x;   // N_*32
    int i = idx & 31, n = idx >> 5;
    float ang = (float)n * exp2f(-(float)i * 0.4152410118609203f);  // log2(10000)/32
    tab[idx] = make_float2(cosf(ang), sinf(ang));
  }
}

// ---- LDS-tiled transpose of Wq AND Wo in one launch: (1024x1024 fp32) -> bf16 transposed ----
__global__ __launch_bounds__(256) void k_transpose2(const float* __restrict__ Wq, const float* __restrict__ Wo,
                                                    u16* __restrict__ WqT, u16* __restrict__ WoT){
  __shared__ float T[64*65];
  int m = blockIdx.x >> 8;
  const float* in = m ? Wo : Wq;
  u16* out = m ? WoT : WqT;
  int bid = blockIdx.x & 255;
  int n0 = (bid & 15) << 6, k0 = (bid >> 4) << 6;
  int tid = threadIdx.x;
  #pragma unroll
  for (int s=0; s<4; ++s){
    int chunk = tid + s*256, r = chunk >> 4, c4 = (chunk & 15) << 2;
    *(f32x4*)(&T[r*65 + c4]) = *(const f32x4*)(&in[(size_t)(k0 + r)*1024 + n0 + c4]);
  }
  __syncthreads();
  #pragma unroll
  for (int s=0; s<2; ++s){
    int chunk = tid + s*256, d = chunk >> 3, c8 = (chunk & 7) << 3;
    u16x4 o1, o2;
    #pragma unroll
    for (int j=0; j<4; ++j){ o1[j] = f2bf(T[(c8+j)*65 + d]); o2[j] = f2bf(T[(c8+4+j)*65 + d]); }
    *(u16x4*)(&out[(size_t)(n0 + d)*1024 + k0 + c8])     = o1;
    *(u16x4*)(&out[(size_t)(n0 + d)*1024 + k0 + c8 + 4]) = o2;
  }
}

// ---- [Wkv | Wkvh | 0] concatenated transpose: out is (192 x 1024) bf16 ----
__global__ void k_build_wkvt(const float* __restrict__ Wkv, const float* __restrict__ Wkvh,
                             u16* __restrict__ out){
  int idx = blockIdx.x*blockDim.x + threadIdx.x;   // over 192*1024
  int n = idx >> 10, k = idx & 1023;
  float v = 0.f;
  if (n < 128)      v = Wkv[k*128 + n];
  else if (n < 160) v = Wkvh[k*32 + (n-128)];
  out[idx] = f2bf(v);
}

// ---- bf16 MFMA GEMM, 64x64 tile (kept for the skinny N=192 KV projection) ----
__global__ __launch_bounds__(256) void k_gemm_bt(const u16* __restrict__ A, const u16* __restrict__ Bt,
                                                 float* __restrict__ C, int M, int N, int K){
  __shared__ u16 As[64*72];
  __shared__ u16 Bs[64*72];
  int ntile = N >> 6;
  int m0 = (blockIdx.x / ntile) << 6;
  int n0 = (blockIdx.x % ntile) << 6;
  int tid = threadIdx.x;
  int w = tid >> 6, l = tid & 63, lr = l & 15, lc = l >> 4;
  int wm = (w >> 1) * 32, wn = (w & 1) * 32;
  f32x4 acc[2][2] = {};
  for (int kt = 0; kt < K; kt += 64){
    __syncthreads();
    #pragma unroll
    for (int s = 0; s < 2; ++s){
      int chunk = tid + s*256;
      int r = chunk >> 3, c8 = (chunk & 7) << 3;
      *(u32x4*)(&As[r*72 + c8]) = *(const u32x4*)(&A[(size_t)(m0 + r)*K + kt + c8]);
      *(u32x4*)(&Bs[r*72 + c8]) = *(const u32x4*)(&Bt[(size_t)(n0 + r)*K + kt + c8]);
    }
    __syncthreads();
    short8 af[2][2], bfr[2][2];
    #pragma unroll
    for (int mf=0; mf<2; ++mf)
      #pragma unroll
      for (int c=0; c<2; ++c)
        af[mf][c] = *(const short8*)(&As[(wm + mf*16 + lr)*72 + c*32 + lc*8]);
    #pragma unroll
    for (int nf=0; nf<2; ++nf)
      #pragma unroll
      for (int c=0; c<2; ++c)
        bfr[nf][c] = *(const short8*)(&Bs[(wn + nf*16 + lr)*72 + c*32 + lc*8]);
    #pragma unroll
    for (int mf=0; mf<2; ++mf)
      #pragma unroll
      for (int nf=0; nf<2; ++nf)
        #pragma unroll
        for (int c=0; c<2; ++c)
          acc[mf][nf] = __builtin_amdgcn_mfma_f32_16x16x32_bf16(af[mf][c], bfr[nf][c], acc[mf][nf], 0,0,0);
  }
  #pragma unroll
  for (int mf=0; mf<2; ++mf)
    #pragma unroll
    for (int nf=0; nf<2; ++nf)
      #pragma unroll
      for (int r=0; r<4; ++r)
        C[(size_t)(m0 + wm + mf*16 + lc*4 + r)*N + n0 + wn + nf*16 + lr] = acc[mf][nf][r];
}

// ---- m97-style 128x128 GEMM. MODE 0: fp32 out. MODE 1: fused rope+scale -> bf16 out (q path) ----
template<int MODE>
__global__ __launch_bounds__(256) void k_gemm128(const u16* __restrict__ A, const u16* __restrict__ Bt,
                                                 void* __restrict__ Cv, const float2* __restrict__ tab,
                                                 int M, int N, int K){
  __shared__ u16 As[128*64];
  __shared__ u16 Bs[128*64];
  int ntile = N >> 7;
  int m0 = (blockIdx.x / ntile) << 7;
  int n0 = (blockIdx.x % ntile) << 7;
  int tid = threadIdx.x;
  int l = tid & 63, lr = l & 15, lc = l >> 4;
  int w = tid >> 6;
  int wm = (w >> 1) * 64, wn = (w & 1) * 64;
  int r_st = tid >> 3, c8_st = (tid & 7) << 3;
  f32x4 acc[4][4] = {};
  for (int kt = 0; kt < K; kt += 64){
    __syncthreads();
    #pragma unroll
    for (int s = 0; s < 4; ++s){
      int r = r_st + s*32;
      __builtin_amdgcn_global_load_lds(
        (const __attribute__((address_space(1))) u32*)(&A[(size_t)(m0 + r)*K + kt + c8_st]),
        (__attribute__((address_space(3))) u32*)(&As[r*64 + c8_st]), 16, 0, 0);
      __builtin_amdgcn_global_load_lds(
        (const __attribute__((address_space(1))) u32*)(&Bt[(size_t)(n0 + r)*K + kt + c8_st]),
        (__attribute__((address_space(3))) u32*)(&Bs[r*64 + c8_st]), 16, 0, 0);
    }
    __syncthreads();
    short8 af[4][2], bfr[4][2];
    #pragma unroll
    for (int m=0; m<4; ++m)
      #pragma unroll
      for (int c=0; c<2; ++c)
        af[m][c] = *(const short8*)(&As[(wm + m*16 + lr)*64 + c*32 + lc*8]);
    #pragma unroll
    for (int n=0; n<4; ++n)
      #pragma unroll
      for (int c=0; c<2; ++c)
        bfr[n][c] = *(const short8*)(&Bs[(wn + n*16 + lr)*64 + c*32 + lc*8]);
    #pragma unroll
    for (int m=0; m<4; ++m)
      #pragma unroll
      for (int n=0; n<4; ++n)
        #pragma unroll
        for (int c=0; c<2; ++c)
          acc[m][n] = __builtin_amdgcn_mfma_f32_16x16x32_bf16(af[m][c], bfr[n][c], acc[m][n], 0,0,0);
  }
  if constexpr (MODE == 0){
    float* C = (float*)Cv;
    #pragma unroll
    for (int m=0; m<4; ++m)
      #pragma unroll
      for (int n=0; n<4; ++n)
        #pragma unroll
        for (int r=0; r<4; ++r)
          C[(size_t)(m0 + wm + m*16 + lc*4 + r)*N + n0 + wn + n*16 + lr] = acc[m][n][r];
  } else {
    u16* C = (u16*)Cv;
    #pragma unroll
    for (int m=0; m<4; ++m){
      int grow = m0 + wm + m*16 + lc*4;
      #pragma unroll
      for (int nf=0; nf<2; ++nf){
        int i = nf*16 + lr;
        #pragma unroll
        for (int r=0; r<4; ++r){
          float2 cs = tab[(size_t)((grow + r) & (N_-1))*32 + i];
          float x1 = acc[m][nf][r], x2 = acc[m][nf+2][r];
          C[(size_t)(grow + r)*N + n0 + wn + i]      = f2bf(0.125f*(x1*cs.x - x2*cs.y));
          C[(size_t)(grow + r)*N + n0 + wn + i + 32] = f2bf(0.125f*(x2*cs.x + x1*cs.y));
        }
      }
    }
  }
}

// ---- fused postproc: proj (ROWS x 192) -> k_rope bf16, gates (b,h,N) fp32, vt (b,64,N) bf16 ----
__global__ __launch_bounds__(256) void k_postproc2(const float* __restrict__ proj, const float2* __restrict__ tab,
                                                   u16* __restrict__ k_rope, float* __restrict__ k_head,
                                                   float* __restrict__ v_head, u16* __restrict__ vt){
  __shared__ u16 Tv[64*72];
  int n0 = blockIdx.x << 6;         // global row base (64 rows, never crosses b)
  int b = n0 >> 11;
  int tid = threadIdx.x;
  // v part -> LDS bf16
  #pragma unroll
  for (int s=0; s<4; ++s){
    int chunk = tid + s*256, r = chunk >> 4, c4 = (chunk & 15) << 2;
    f32x4 v = *(const f32x4*)(&proj[(size_t)(n0+r)*192 + 64 + c4]);
    u16x4 o; o[0]=f2bf(v[0]); o[1]=f2bf(v[1]); o[2]=f2bf(v[2]); o[3]=f2bf(v[3]);
    *(u16x4*)(&Tv[r*72 + c4]) = o;
  }
  // rope + gates: each wave sweeps rows wv, wv+4, ...
  int wv = tid>>6, t = tid&63;
  for (int rr = wv; rr < 64; rr += 4){
    int row = n0 + rr, n = row & (N_-1);
    const float* p = proj + (size_t)row*192;
    if (t < 32){
      float hv = 1.f/(1.f + __expf(-p[128 + t]));
      if (t < 16) k_head[((size_t)b*16 + t)*N_ + n] = hv * LOG2E;   // log2e folded
      else        v_head[((size_t)b*16 + (t-16))*N_ + n] = hv;
      float2 cs = tab[n*32 + t];
      float k1 = p[t], k2 = p[32 + t];
      k_rope[(size_t)row*64 + t]      = f2bf(k1*cs.x - k2*cs.y);
      k_rope[(size_t)row*64 + 32 + t] = f2bf(k2*cs.x + k1*cs.y);
    }
  }
  __syncthreads();
  int nb = n0 & (N_-1);
  #pragma unroll
  for (int s=0; s<2; ++s){
    int chunk = tid + s*256, d = chunk>>3, c8 = (chunk&7)<<3;
    u32x4 o; u16* op = (u16*)&o;
    #pragma unroll
    for (int j=0; j<8; ++j) op[j] = Tv[(c8+j)*72 + d];
    *(u32x4*)(&vt[((size_t)b*64 + d)*N_ + nb + c8]) = o;
  }
}

// ---- flash attention v4: KVBLK=128, register-prefetch double-stage (T14), shfl transports ----
__global__ __launch_bounds__(256, 2) void k_attn4(const u16* __restrict__ q_bf, const u16* __restrict__ k_rp,
                                                  const u16* __restrict__ vt, const float* __restrict__ k_hd,
                                                  const float* __restrict__ v_hd, u16* __restrict__ attn_o){
  __shared__ u16 Ks[128*72];       // [key 0..127][hd]
  __shared__ u16 Vts[64*136];      // [hd][key 0..127]
  __shared__ u16 Ps[4][16*136];    // per-wave P tile [q][k 0..127]
  __shared__ float g_s[256];       // gk[0..127] | gv[0..127]
  int z = blockIdx.x;
  int h = z & 15, pidx = (z >> 4) & 15, b = z >> 8;
  int qta = pidx, qtb = 31 - pidx;
  int ta_max = qta >> 1, tb_max = qtb >> 1;
  int tid = threadIdx.x, w = tid>>6, l = tid&63, lr = l&15, lc = l>>4;
  size_t rowbase = (size_t)b*N_;
  size_t qoff_a = (rowbase + qta*64 + w*16 + lr)*1024 + h*64;
  size_t qoff_b = (rowbase + qtb*64 + w*16 + lr)*1024 + h*64;
  short8 qa0 = *(const short8*)(&q_bf[qoff_a + lc*8]);
  short8 qa1 = *(const short8*)(&q_bf[qoff_a + 32 + lc*8]);
  short8 qb0 = *(const short8*)(&q_bf[qoff_b + lc*8]);
  short8 qb1 = *(const short8*)(&q_bf[qoff_b + 32 + lc*8]);
  const float* gkp = k_hd + ((size_t)b*16 + h)*N_;
  const float* gvp = v_hd + ((size_t)b*16 + h)*N_;
  // prefetch registers
  u32x4 kr[4], vr[4]; float gr;
  auto issue = [&](int t){
    int kg0 = t << 7;
    #pragma unroll
    for (int s=0; s<4; ++s){
      int chunk = tid + s*256;
      int r = chunk>>3, c8 = (chunk&7)<<3;
      kr[s] = *(const u32x4*)(&k_rp[(rowbase + kg0 + r)*64 + c8]);
      int d = chunk>>4, c8v = (chunk&15)<<3;
      vr[s] = *(const u32x4*)(&vt[((size_t)b*64 + d)*N_ + kg0 + c8v]);
    }
    gr = (tid < 128) ? gkp[kg0 + tid] : gvp[kg0 + tid - 128];
  };
  float ma = -1e30f, la = 0.f, mb = -1e30f, lb = 0.f;
  f32x4 oa[4] = {}, ob[4] = {};

  auto process = [&](short8 q0, short8 q1, f32x4 (&o)[4], float& mR, float& lR, int qtt, int t){
    int kg0 = t << 7;
    // S^T = K * Q^T : lane (lr,lc) holds P[q=lr][k = kg0 + nf*16 + lc*4 + r], nf=0..7
    f32x4 s4[8];
    #pragma unroll
    for (int nf=0; nf<8; ++nf){
      short8 kf0 = *(const short8*)(&Ks[(nf*16+lr)*72 + lc*8]);
      short8 kf1 = *(const short8*)(&Ks[(nf*16+lr)*72 + 32 + lc*8]);
      f32x4 zz = {};
      zz = __builtin_amdgcn_mfma_f32_16x16x32_bf16(kf0, q0, zz, 0,0,0);
      s4[nf] = __builtin_amdgcn_mfma_f32_16x16x32_bf16(kf1, q1, zz, 0,0,0);
    }
    // gates
    #pragma unroll
    for (int nf=0; nf<8; ++nf){
      f32x4 gkv = *(const f32x4*)(&g_s[nf*16 + lc*4]);
      #pragma unroll
      for (int r=0; r<4; ++r) s4[nf][r] *= gkv[r];
    }
    if (t == (qtt >> 1)){
      int qg = qtt*64 + w*16 + lr;
      #pragma unroll
      for (int nf=0; nf<8; ++nf)
        #pragma unroll
        for (int r=0; r<4; ++r)
          if (kg0 + nf*16 + lc*4 + r > qg) s4[nf][r] = -1e30f;
    }
    // softmax over 32 vals/lane + cross-lane (rows share lr across lc groups)
    float rm = -1e30f;
    #pragma unroll
    for (int nf=0; nf<8; ++nf){
      float a = fmaxf(fmaxf(s4[nf][0], s4[nf][1]), fmaxf(s4[nf][2], s4[nf][3]));
      rm = fmaxf(rm, a);
    }
    rm = fmaxf(rm, __shfl_xor(rm, 16));
    rm = fmaxf(rm, __shfl_xor(rm, 32));
    float mn = fmaxf(mR, rm);
    float al = exp2f(mR - mn);
    mR = mn;
    float ps = 0.f;
    #pragma unroll
    for (int nf=0; nf<8; ++nf)
      #pragma unroll
      for (int r=0; r<4; ++r){ s4[nf][r] = exp2f(s4[nf][r] - mn); ps += s4[nf][r]; }
    ps += __shfl_xor(ps, 16);
    ps += __shfl_xor(ps, 32);
    lR = lR*al + ps;
    // fold v-gate, pack to bf16, write wave-private P
    #pragma unroll
    for (int nf=0; nf<8; ++nf){
      f32x4 gvv = *(const f32x4*)(&g_s[128 + nf*16 + lc*4]);
      u32 lo = cvtpk(s4[nf][0]*gvv[0], s4[nf][1]*gvv[1]);
      u32 hi = cvtpk(s4[nf][2]*gvv[2], s4[nf][3]*gvv[3]);
      *(u32x2*)(&Ps[w][lr*136 + nf*16 + lc*4]) = (u32x2){lo, hi};
    }
    asm volatile("s_waitcnt lgkmcnt(0)" ::: "memory");
    __builtin_amdgcn_sched_barrier(0);
    // al in D-layout rows via shfl (al uniform over lanes with same lr)
    f32x4 alv;
    #pragma unroll
    for (int r=0; r<4; ++r) alv[r] = __shfl(al, lc*4 + r, 16);
    short8 pf[4];
    #pragma unroll
    for (int c=0; c<4; ++c) pf[c] = *(const short8*)(&Ps[w][lr*136 + c*32 + lc*8]);
    #pragma unroll
    for (int nf=0; nf<4; ++nf){
      #pragma unroll
      for (int r=0; r<4; ++r) o[nf][r] *= alv[r];
      #pragma unroll
      for (int c=0; c<4; ++c){
        short8 vf = *(const short8*)(&Vts[(nf*16+lr)*136 + c*32 + lc*8]);
        o[nf] = __builtin_amdgcn_mfma_f32_16x16x32_bf16(pf[c], vf, o[nf], 0,0,0);
      }
    }
  };

  issue(0);
  for (int t = 0; t <= tb_max; ++t){
    __syncthreads();                 // prior compute's LDS reads done
    #pragma unroll
    for (int s=0; s<4; ++s){
      int chunk = tid + s*256;
      int r = chunk>>3, c8 = (chunk&7)<<3;
      *(u32x4*)(&Ks[r*72 + c8]) = kr[s];
      int d = chunk>>4, c8v = (chunk&15)<<3;
      *(u32x4*)(&Vts[d*136 + c8v]) = vr[s];
    }
    g_s[tid] = gr;
    if (t < tb_max) issue(t+1);      // prefetch next tile; latency hides under compute
    __syncthreads();                 // LDS ready
    process(qb0, qb1, ob, mb, lb, qtb, t);
    if (t <= ta_max) process(qa0, qa1, oa, ma, la, qta, t);
  }
  // epilogue: l via shfl, normalize, store (o: row q = lc*4+r, col d = nf*16+lr)
  auto store_tile = [&](f32x4 (&o)[4], float lR, int qtt){
    f32x4 lv;
    #pragma unroll
    for (int r=0; r<4; ++r) lv[r] = __builtin_amdgcn_rcpf(__shfl(lR, lc*4 + r, 16));
    #pragma unroll
    for (int nf=0; nf<4; ++nf)
      #pragma unroll
      for (int r=0; r<4; ++r)
        attn_o[(rowbase + qtt*64 + w*16 + lc*4 + r)*1024 + h*64 + nf*16 + lr] = f2bf(o[nf][r] * lv[r]);
  };
  store_tile(ob, lb, qtb);
  store_tile(oa, la, qta);
}

extern "C" void kernel_launch(void* const* d_in, const int* in_sizes, int n_in,
                              void* d_out, int out_size, void* d_ws, size_t ws_size,
                              hipStream_t stream){
  const float* x    = (const float*)d_in[0];
  const float* Wq   = (const float*)d_in[1];
  const float* Wkv  = (const float*)d_in[2];
  const float* Wkvh = (const float*)d_in[3];
  const float* Wo   = (const float*)d_in[4];
  float* out = (float*)d_out;

  char* p = (char*)d_ws;
  u16* xb      = (u16*)p;   p += (size_t)ROWS*1024*2;   // 8 MB (reused as attn_o later)
  u16* WqT     = (u16*)p;   p += (size_t)1024*1024*2;   // 2 MB
  u16* WoT     = (u16*)p;   p += (size_t)1024*1024*2;   // 2 MB
  u16* WkvT    = (u16*)p;   p += (size_t)192*1024*2;    // 384 KB
  float* proj  = (float*)p; p += (size_t)ROWS*192*4;    // 3 MB
  u16* q_bf    = (u16*)p;   p += (size_t)ROWS*1024*2;   // 8 MB
  u16* k_rp    = (u16*)p;   p += (size_t)ROWS*64*2;     // 512 KB
  u16* vt      = (u16*)p;   p += (size_t)B_*64*N_*2;    // 512 KB (b,64,N)
  float* k_hd  = (float*)p; p += (size_t)B_*H_*N_*4;    // 256 KB (b,h,N), log2e folded
  float* v_hd  = (float*)p; p += (size_t)B_*H_*N_*4;    // 256 KB (b,h,N)
  float2* tab  = (float2*)p; p += (size_t)N_*32*8;      // 512 KB rope trig
  u16* attn_o  = xb;  // xb dead after the two projection GEMMs

  k_prep<<<4096 + N_*32/256, 256, 0, stream>>>(x, xb, tab);
  k_transpose2<<<512, 256, 0, stream>>>(Wq, Wo, WqT, WoT);
  k_build_wkvt<<<192*1024/256, 256, 0, stream>>>(Wkv, Wkvh, WkvT);
  k_gemm128<1><<<(ROWS/128)*(1024/128), 256, 0, stream>>>(xb, WqT, q_bf, tab, ROWS, 1024, 1024);
  k_gemm_bt<<<(ROWS/64)*(192/64), 256, 0, stream>>>(xb, WkvT, proj, ROWS, 192, 1024);
  k_postproc2<<<ROWS/64, 256, 0, stream>>>(proj, tab, k_rp, k_hd, v_hd, vt);
  k_attn4<<<B_*H_*16, 256, 0, stream>>>(q_bf, k_rp, vt, k_hd, v_hd, attn_o);
  k_gemm128<0><<<(ROWS/128)*(1024/128), 256, 0, stream>>>(attn_o, WoT, out, nullptr, ROWS, 1024, 1024);
}